// Round 1
// baseline (102.413 us; speedup 1.0000x reference)
//
#include <hip/hip_runtime.h>

#define NB_BS   2048
#define NB_NINP 512
#define NB_NHID 512
#define NB_K    16
#define NB_T    8
#define NB_M    32
#define NB_C    768   // T * 3 * M
#define NB_ATT  16
#define H_OUT_ELEMS (NB_BS * NB_NHID)   // 1048576

// ---------------------------------------------------------------------------
// Kernel 1: gi[b][c] = sum_i x[b][i] * Wih[c][i] + bih[c]
//   x: [2048][512], Wih flat: [768][512] (c = t*96 + gate*32 + j), gi: [2048][768]
// Classic 64x64 tile, BK=32, 256 threads, 4x4 micro-tile, b128 fragment reads.
// ---------------------------------------------------------------------------
__global__ __launch_bounds__(256, 4)
void k1_gemm_gi(const float* __restrict__ x, const float* __restrict__ Wih,
                const float* __restrict__ bih, float* __restrict__ gi)
{
    // pad 68 keeps 16B alignment for float4 reads and spreads banks
    __shared__ __align__(16) float As[32][68];
    __shared__ __align__(16) float Bs[32][68];

    const int tid  = threadIdx.x;
    const int bc   = blockIdx.x;        // 0..11 (col tiles)
    const int br   = blockIdx.y;        // 0..31 (row tiles)
    const int row0 = br * 64, col0 = bc * 64;
    const int lrow = tid >> 2;          // 0..63
    const int lk   = (tid & 3) * 8;     // 0,8,16,24
    const int tr   = tid >> 4;          // 0..15
    const int tc   = tid & 15;          // 0..15

    const float* xp = x   + (size_t)(row0 + lrow) * NB_NINP + lk;
    const float* wp = Wih + (size_t)(col0 + lrow) * NB_NINP + lk;

    float4 a0 = *(const float4*)(xp);
    float4 a1 = *(const float4*)(xp + 4);
    float4 b0 = *(const float4*)(wp);
    float4 b1 = *(const float4*)(wp + 4);

    float acc[4][4];
    #pragma unroll
    for (int i = 0; i < 4; ++i)
        #pragma unroll
        for (int j = 0; j < 4; ++j) acc[i][j] = 0.f;

    for (int kb = 0; kb < NB_NINP; kb += 32) {
        __syncthreads();
        As[lk+0][lrow]=a0.x; As[lk+1][lrow]=a0.y; As[lk+2][lrow]=a0.z; As[lk+3][lrow]=a0.w;
        As[lk+4][lrow]=a1.x; As[lk+5][lrow]=a1.y; As[lk+6][lrow]=a1.z; As[lk+7][lrow]=a1.w;
        Bs[lk+0][lrow]=b0.x; Bs[lk+1][lrow]=b0.y; Bs[lk+2][lrow]=b0.z; Bs[lk+3][lrow]=b0.w;
        Bs[lk+4][lrow]=b1.x; Bs[lk+5][lrow]=b1.y; Bs[lk+6][lrow]=b1.z; Bs[lk+7][lrow]=b1.w;
        __syncthreads();
        if (kb + 32 < NB_NINP) {   // prefetch next K-slab, overlaps compute below
            a0 = *(const float4*)(xp + kb + 32);
            a1 = *(const float4*)(xp + kb + 36);
            b0 = *(const float4*)(wp + kb + 32);
            b1 = *(const float4*)(wp + kb + 36);
        }
        #pragma unroll
        for (int kk = 0; kk < 32; ++kk) {
            const float4 av = *(const float4*)&As[kk][tr * 4];
            const float4 wv = *(const float4*)&Bs[kk][tc * 4];
            acc[0][0] = fmaf(av.x, wv.x, acc[0][0]);
            acc[0][1] = fmaf(av.x, wv.y, acc[0][1]);
            acc[0][2] = fmaf(av.x, wv.z, acc[0][2]);
            acc[0][3] = fmaf(av.x, wv.w, acc[0][3]);
            acc[1][0] = fmaf(av.y, wv.x, acc[1][0]);
            acc[1][1] = fmaf(av.y, wv.y, acc[1][1]);
            acc[1][2] = fmaf(av.y, wv.z, acc[1][2]);
            acc[1][3] = fmaf(av.y, wv.w, acc[1][3]);
            acc[2][0] = fmaf(av.z, wv.x, acc[2][0]);
            acc[2][1] = fmaf(av.z, wv.y, acc[2][1]);
            acc[2][2] = fmaf(av.z, wv.z, acc[2][2]);
            acc[2][3] = fmaf(av.z, wv.w, acc[2][3]);
            acc[3][0] = fmaf(av.w, wv.x, acc[3][0]);
            acc[3][1] = fmaf(av.w, wv.y, acc[3][1]);
            acc[3][2] = fmaf(av.w, wv.z, acc[3][2]);
            acc[3][3] = fmaf(av.w, wv.w, acc[3][3]);
        }
    }

    const float4 bv = *(const float4*)&bih[col0 + tc * 4];
    #pragma unroll
    for (int i = 0; i < 4; ++i) {
        float4 o;
        o.x = acc[i][0] + bv.x; o.y = acc[i][1] + bv.y;
        o.z = acc[i][2] + bv.z; o.w = acc[i][3] + bv.w;
        *(float4*)&gi[(size_t)(row0 + tr * 4 + i) * NB_C + col0 + tc * 4] = o;
    }
}

// ---------------------------------------------------------------------------
// Kernel 2: per (b,k): gh = h2 @ W_hh^T, GRU gates, write-key logits,
//           gumbel-argmax, gather hnext row + one-hot att.
// 256 blocks x 512 threads (8 waves). Wave w owns b = blockIdx*8 + w.
// Lane lane: m_ = lane&31, half = lane>>5; pair p -> template t = 2p + half.
// Lane-local gate triple (r,z,n) for 4 (t,m) pairs -> GRU fully in registers.
// ---------------------------------------------------------------------------
__global__ __launch_bounds__(512, 2)
void k2_fused(const float* __restrict__ h,      const float* __restrict__ Whh,
              const float* __restrict__ bhh,    const float* __restrict__ wread,
              const float* __restrict__ wwrite, const float* __restrict__ gumb,
              const float* __restrict__ gi,     float* __restrict__ out)
{
    // WT[mm][c] with row pitch 769: conflict-free for both staging writes
    // (lanes vary m) and inner-loop reads (lanes vary j): bank=(mm+c)%32.
    __shared__ float WT[32 * 769];          // 98432 B
    __shared__ float WWT[NB_T * NB_ATT * NB_M]; // w_write^T [t][f][m], 16 KB
    __shared__ float WR[NB_M * NB_ATT];     // w_read [m][f], 2 KB
    __shared__ float HROW[8 * NB_NHID];     // per-wave h row, 16 KB

    const int tid  = threadIdx.x;
    const int wave = tid >> 6;
    const int lane = tid & 63;
    const int m_   = lane & 31;
    const int half = lane >> 5;
    const int b    = blockIdx.x * 8 + wave;

    // ---- stage shared operands ----
    for (int i = tid; i < 24576; i += 512) {          // W_hh flat [c][m] = c*32+m
        WT[(i & 31) * 769 + (i >> 5)] = Whh[i];
    }
    for (int i = tid; i < 4096; i += 512) {           // w_write flat [t][m][f]
        const int t = i >> 9, m2 = (i >> 4) & 31, f = i & 15;
        WWT[t * 512 + f * 32 + m2] = wwrite[i];
    }
    if (tid < 512) WR[tid] = wread[tid];
    {   // this wave's h row (512 floats)
        const float4* hp = (const float4*)(h + (size_t)b * NB_NHID);
        float4* hs = (float4*)(HROW + wave * NB_NHID);
        hs[lane]      = hp[lane];
        hs[lane + 64] = hp[lane + 64];
    }
    __syncthreads();   // only barrier needed; all LDS is read-only after this

    // ---- per-lane constants: gi (with b_ih folded) and b_hh at this lane's
    //      12 gate positions c = (2p+half)*96 + gate*32 + m_ (same for all k!)
    float gi_r[4][3], bh_r[4][3];
    #pragma unroll
    for (int p = 0; p < 4; ++p)
        #pragma unroll
        for (int gc = 0; gc < 3; ++gc) {
            const int c = (2 * p + half) * 96 + gc * 32 + m_;
            gi_r[p][gc] = gi[(size_t)b * NB_C + c];
            bh_r[p][gc] = bhh[c];
        }

    const float* hrow_w = HROW + wave * NB_NHID;

    #pragma unroll 1
    for (int g = 0; g < 2; ++g) {           // two groups of 8 k's
        float acc[8][12];
        #pragma unroll
        for (int r = 0; r < 8; ++r)
            #pragma unroll
            for (int j = 0; j < 12; ++j) acc[r][j] = 0.f;

        // ---- gh GEMM: outer-product over contraction m (mm), broadcast h2 ----
        const float* wtbase = WT + half * 96 + m_;
        const float* hvbase = hrow_w + g * 256;
        for (int mm = 0; mm < 32; ++mm) {
            const float* wtp = wtbase + mm * 769;
            const float* hvp = hvbase + mm;
            float w[12], hv[8];
            #pragma unroll
            for (int p = 0; p < 4; ++p)
                #pragma unroll
                for (int gc = 0; gc < 3; ++gc)
                    w[p * 3 + gc] = wtp[p * 192 + gc * 32];
            #pragma unroll
            for (int r = 0; r < 8; ++r) hv[r] = hvp[r * 32];
            #pragma unroll
            for (int r = 0; r < 8; ++r)
                #pragma unroll
                for (int j = 0; j < 12; ++j)
                    acc[r][j] = fmaf(hv[r], w[j], acc[r][j]);
        }

        // ---- epilogue per k ----
        #pragma unroll
        for (int r = 0; r < 8; ++r) {
            const int k = g * 8 + r;
            // h_read[f] on lanes 0..15 (f = lane&15), then broadcast via shfl
            float hrv = 0.f;
            {
                const int f = lane & 15;
                const float* hq = hrow_w + k * 32;
                #pragma unroll
                for (int m2 = 0; m2 < 32; ++m2)
                    hrv = fmaf(hq[m2], WR[m2 * 16 + f], hrv);
            }
            float hr[16];
            #pragma unroll
            for (int f = 0; f < 16; ++f) hr[f] = __shfl(hrv, f, 64);

            const float h2v = hrow_w[k * 32 + m_];
            float hn[4], lg[4];
            #pragma unroll
            for (int p = 0; p < 4; ++p) {
                const float xr  = gi_r[p][0] + bh_r[p][0] + acc[r][p * 3 + 0];
                const float xz  = gi_r[p][1] + bh_r[p][1] + acc[r][p * 3 + 1];
                const float ghn = bh_r[p][2] + acc[r][p * 3 + 2];
                const float rg  = 1.f / (1.f + __expf(-xr));
                const float zg  = 1.f / (1.f + __expf(-xz));
                const float xn  = gi_r[p][2] + rg * ghn;
                const float e2  = __expf(2.f * xn);
                const float tn  = 1.f - 2.f / (e2 + 1.f);   // tanh(xn)
                const float hv2 = (1.f - zg) * tn + zg * h2v;
                hn[p] = hv2;
                // ww[t][m_] = sum_f w_write[t][m_][f] * h_read[f]
                const int t = 2 * p + half;
                const float* wq = WWT + t * 512 + m_;
                float ww = 0.f;
                #pragma unroll
                for (int f = 0; f < 16; ++f) ww = fmaf(wq[f * 32], hr[f], ww);
                // logit partial, reduce over the 32 m-lanes of this half
                float part = hv2 * ww;
                part += __shfl_xor(part, 1, 64);
                part += __shfl_xor(part, 2, 64);
                part += __shfl_xor(part, 4, 64);
                part += __shfl_xor(part, 8, 64);
                part += __shfl_xor(part, 16, 64);
                lg[p] = part;
            }
            // assemble all 8 logits (exchange halves)
            float s[8];
            #pragma unroll
            for (int p = 0; p < 4; ++p) {
                const float oth = __shfl_xor(lg[p], 32, 64);
                s[2 * p]     = half ? oth   : lg[p];
                s[2 * p + 1] = half ? lg[p] : oth;
            }
            // gumbel + first-max argmax (matches np.argmax semantics)
            const float* gp = gumb + (size_t)(b * NB_K + k) * NB_T;
            float best = s[0] + gp[0];
            int bt = 0;
            #pragma unroll
            for (int t2 = 1; t2 < 8; ++t2) {
                const float v = s[t2] + gp[t2];
                if (v > best) { best = v; bt = t2; }
            }
            // h_out: half-wave holding template bt writes its 32 hnext values
            const int pstar = bt >> 1, hstar = bt & 1;
            float hsel = hn[0];
            hsel = (pstar == 1) ? hn[1] : hsel;
            hsel = (pstar == 2) ? hn[2] : hsel;
            hsel = (pstar == 3) ? hn[3] : hsel;
            if (half == hstar)
                out[(size_t)b * NB_NHID + k * 32 + m_] = hsel;
            if (lane < 8)
                out[H_OUT_ELEMS + (size_t)(b * NB_K + k) * NB_T + lane] =
                    (lane == bt) ? 1.f : 0.f;
        }
    }
}

extern "C" void kernel_launch(void* const* d_in, const int* in_sizes, int n_in,
                              void* d_out, int out_size, void* d_ws, size_t ws_size,
                              hipStream_t stream) {
    const float* x      = (const float*)d_in[0];
    const float* h      = (const float*)d_in[1];
    const float* Wih    = (const float*)d_in[2];
    const float* Whh    = (const float*)d_in[3];
    const float* bih    = (const float*)d_in[4];
    const float* bhh    = (const float*)d_in[5];
    const float* wread  = (const float*)d_in[6];
    const float* wwrite = (const float*)d_in[7];
    const float* gumb   = (const float*)d_in[8];
    float* out = (float*)d_out;
    float* gi  = (float*)d_ws;   // 2048*768*4 = 6 MB scratch

    dim3 g1(NB_C / 64, NB_BS / 64);   // (12, 32)
    k1_gemm_gi<<<g1, dim3(256), 0, stream>>>(x, Wih, bih, gi);
    k2_fused<<<dim3(NB_BS / 8), dim3(512), 0, stream>>>(h, Whh, bhh, wread,
                                                        wwrite, gumb, gi, out);
}